// Round 10
// baseline (885.933 us; speedup 1.0000x reference)
//
#include <hip/hip_runtime.h>
#include <math.h>

#define N_NODES 30000
#define N_EDGES 480000
#define HDIM 128
#define EPB 64        // edges (or nodes) per MFMA block; max node degree (~40)
                      // must be < EPB so a node's CSR range spans <=2 blocks.
#define NAS 264       // node A-tile row stride (bf16)
#define MS 136        // m1/m2 row stride (bf16)

typedef __attribute__((ext_vector_type(8))) short short8b;
typedef __attribute__((ext_vector_type(4))) float f32x4;

__device__ __forceinline__ float silu_f(float v) {
  return v / (1.0f + __expf(-v));
}

__device__ __forceinline__ unsigned short f2bf(float f) {
  unsigned int u = __float_as_uint(f);
  unsigned int r = u + 0x7fffu + ((u >> 16) & 1u);
  return (unsigned short)(r >> 16);
}

__device__ __forceinline__ float bf2f(unsigned short u) {
  return __uint_as_float((unsigned int)u << 16);
}

// ---------------- output init: out = [h | x] ----------------
__global__ void init_out_kernel(const float* __restrict__ h,
                                const float* __restrict__ x,
                                float* __restrict__ out) {
  int idx = blockIdx.x * 256 + threadIdx.x;
  out[idx] = h[idx];
  if (idx < N_NODES * 3) out[N_NODES * HDIM + idx] = x[idx];
}

// ---------------- weight convert: W[K][128] fp32 -> [KT][128][32] bf16 ----
__global__ void convert_w_kernel(const float* __restrict__ W,
                                 ushort* __restrict__ dst, int Kreal, int KT) {
  int idx = blockIdx.x * 256 + threadIdx.x;
  if (idx >= KT * 4096) return;
  int kt = idx >> 12, rem = idx & 4095, n = rem >> 5, kk = rem & 31;
  int k = kt * 32 + kk;
  float v = (k < Kreal) ? W[(size_t)k * HDIM + n] : 0.0f;
  dst[idx] = f2bf(v);
}

// ---------------- counting sort of edges by destination row ----------------
__global__ void count_kernel(const int* __restrict__ ei, int* __restrict__ cursor) {
  int e = blockIdx.x * 256 + threadIdx.x;
  atomicAdd(&cursor[ei[e]], 1);
}

__global__ __launch_bounds__(1024) void scan_kernel(int* __restrict__ cursor,
                                                    int* __restrict__ cstart) {
  __shared__ int sums[1024];
  const int tid = threadIdx.x;
  const int base = tid * 30;
  int local[30];
  int s = 0;
#pragma unroll
  for (int j = 0; j < 30; ++j) {
    int idx = base + j;
    int d = (idx < N_NODES) ? cursor[idx] : 0;
    local[j] = s;
    s += d;
  }
  sums[tid] = s;
  __syncthreads();
  for (int off = 1; off < 1024; off <<= 1) {
    int add = (tid >= off) ? sums[tid - off] : 0;
    __syncthreads();
    sums[tid] += add;
    __syncthreads();
  }
  int excl = (tid == 0) ? 0 : sums[tid - 1];
#pragma unroll
  for (int j = 0; j < 30; ++j) {
    int idx = base + j;
    if (idx < N_NODES) {
      int v = excl + local[j];
      cursor[idx] = v;
      cstart[idx] = v;
    }
  }
}

__global__ void fill_kernel(const int* __restrict__ ei, int* __restrict__ cursor,
                            int* __restrict__ elist) {
  int e = blockIdx.x * 256 + threadIdx.x;
  int r = ei[e];
  int pos = atomicAdd(&cursor[r], 1);   // after: cursor[n] = CSR end
  elist[pos] = e;
}

// ---------------- CNOT ring permutation ----------------
__global__ void perm_kernel(int* __restrict__ g) {
  int i = threadIdx.x;
  int v = i;
  const int cs[7] = {6, 5, 4, 3, 2, 1, 0};
  const int ts[7] = {0, 6, 5, 4, 3, 2, 1};
#pragma unroll
  for (int p = 0; p < 7; ++p) {
    int cb = (v >> (6 - cs[p])) & 1;
    v = v ^ (cb << (6 - ts[p]));
  }
  g[i] = v;
}

// ============ Newton-Schulz inverse of B = A_h + iI (verified R6/R8) ======
__global__ void ns_init_kernel(const float* __restrict__ Are,
                               const float* __restrict__ Aim,
                               float2* __restrict__ X) {
  int lj = blockIdx.y;
  int idx = blockIdx.x * 256 + threadIdx.x;
  int r = idx >> 7, c = idx & 127;
  const float* are = Are + (size_t)lj * 16384;
  const float* aim = Aim + (size_t)lj * 16384;
  float re = are[r * 128 + c] + are[c * 128 + r];
  float im = aim[r * 128 + c] - aim[c * 128 + r];
  if (r == c) im -= 1.0f;
  X[(size_t)lj * 16384 + idx] = make_float2(re, im);
}

__global__ void ns_bx_kernel(const float* __restrict__ Are,
                             const float* __restrict__ Aim,
                             const float2* __restrict__ X,
                             float2* __restrict__ T) {
  int lj = blockIdx.y;
  int idx = blockIdx.x * 256 + threadIdx.x;
  int r = idx >> 7, c = idx & 127;
  const float* are = Are + (size_t)lj * 16384;
  const float* aim = Aim + (size_t)lj * 16384;
  const float2* x = X + (size_t)lj * 16384;
  float2 acc = make_float2(0.f, 0.f);
  for (int k = 0; k < 128; ++k) {
    float re = are[r * 128 + k] + are[k * 128 + r];
    float im = aim[r * 128 + k] - aim[k * 128 + r];
    if (k == r) im += 1.0f;
    float2 b = x[k * 128 + c];
    acc.x += re * b.x - im * b.y;
    acc.y += re * b.y + im * b.x;
  }
  T[(size_t)lj * 16384 + idx] = acc;
}

__global__ void ns_upd_kernel(const float2* __restrict__ X,
                              const float2* __restrict__ T,
                              float2* __restrict__ Xn) {
  int lj = blockIdx.y;
  int idx = blockIdx.x * 256 + threadIdx.x;
  int r = idx >> 7, c = idx & 127;
  const float2* x = X + (size_t)lj * 16384;
  const float2* t = T + (size_t)lj * 16384;
  float2 acc = make_float2(0.f, 0.f);
  for (int k = 0; k < 128; ++k) {
    float2 a = x[r * 128 + k];
    float2 b = t[k * 128 + c];
    acc.x += a.x * b.x - a.y * b.y;
    acc.y += a.x * b.y + a.y * b.x;
  }
  float2 xc = x[r * 128 + c];
  Xn[(size_t)lj * 16384 + idx] = make_float2(2.f * xc.x - acc.x, 2.f * xc.y - acc.y);
}

// ---------------- q = (A_h - iI) * Binv ----------------
__global__ void qmat_kernel(const float* __restrict__ Are,
                            const float* __restrict__ Aim,
                            const float2* __restrict__ binvg,
                            float2* __restrict__ qm) {
  int lj = blockIdx.y;
  int idx = blockIdx.x * 256 + threadIdx.x;
  int r = idx >> 7, c = idx & 127;
  const float* are = Are + (size_t)lj * 16384;
  const float* aim = Aim + (size_t)lj * 16384;
  const float2* binv = binvg + (size_t)lj * 16384;
  float2 acc = make_float2(0.f, 0.f);
  for (int k = 0; k < 128; ++k) {
    float re = are[r * 128 + k] + are[k * 128 + r];
    float im = aim[r * 128 + k] - aim[k * 128 + r];
    if (k == r) im -= 1.0f;
    float2 b = binv[k * 128 + c];
    acc.x += re * b.x - im * b.y;
    acc.y += re * b.y + im * b.x;
  }
  qm[(size_t)lj * 16384 + idx] = acc;
}

// ---------------- Gk = (RY*RX)^(kron 7) ----------------
__global__ void gk_kernel(const float* __restrict__ coeffs,
                          float2* __restrict__ gkm) {
  int lj = blockIdx.y;
  float a = coeffs[lj * 2 + 0], b = coeffs[lj * 2 + 1];
  float ca = cosf(0.5f * a), sa = sinf(0.5f * a);
  float cb = cosf(0.5f * b), sb = sinf(0.5f * b);
  float2 G[2][2];
  G[0][0] = make_float2(cb * ca, sb * sa);
  G[0][1] = make_float2(-sb * ca, -cb * sa);
  G[1][0] = make_float2(sb * ca, -cb * sa);
  G[1][1] = make_float2(cb * ca, -sb * sa);
  int idx = blockIdx.x * 256 + threadIdx.x;
  int r = idx >> 7, c = idx & 127;
  float2 acc = make_float2(1.f, 0.f);
#pragma unroll
  for (int bit = 6; bit >= 0; --bit) {
    float2 g = G[(r >> bit) & 1][(c >> bit) & 1];
    acc = make_float2(acc.x * g.x - acc.y * g.y, acc.x * g.y + acc.y * g.x);
  }
  gkm[(size_t)lj * 16384 + idx] = acc;
}

// ---------------- N_j[i][c] = sum_k q[k][i] * Gk[g[c]][k] ----------------
__global__ void nj_kernel(const float2* __restrict__ qm,
                          const float2* __restrict__ gkm,
                          const int* __restrict__ g,
                          float2* __restrict__ njm) {
  int lj = blockIdx.y;
  int idx = blockIdx.x * 256 + threadIdx.x;
  int i = idx >> 7, c = idx & 127;
  int gc = g[c];
  const float2* q = qm + (size_t)lj * 16384;
  const float2* gk = gkm + (size_t)lj * 16384;
  float2 acc = make_float2(0.f, 0.f);
  for (int k = 0; k < 128; ++k) {
    float2 qa = q[k * 128 + i];
    float2 gb = gk[gc * 128 + k];
    acc.x += qa.x * gb.x - qa.y * gb.y;
    acc.y += qa.x * gb.y + qa.y * gb.x;
  }
  njm[(size_t)lj * 16384 + idx] = acc;
}

// ---------------- U_l = N_{l,0} @ N_{l,1} ----------------
__global__ void compose_kernel(const float2* __restrict__ njm,
                               float2* __restrict__ um) {
  int l = blockIdx.y;
  int idx = blockIdx.x * 256 + threadIdx.x;
  int i = idx >> 7, c = idx & 127;
  const float2* n0 = njm + (size_t)(l * 2 + 0) * 16384;
  const float2* n1 = njm + (size_t)(l * 2 + 1) * 16384;
  float2 acc = make_float2(0.f, 0.f);
  for (int k = 0; k < 128; ++k) {
    float2 a = n0[i * 128 + k];
    float2 b = n1[k * 128 + c];
    acc.x += a.x * b.x - a.y * b.y;
    acc.y += a.x * b.y + a.y * b.x;
  }
  um[(size_t)l * 16384 + idx] = acc;
}

// ---------------- Wqd_l = Re(U_l) @ dec_w_l ----------------
__global__ void wqd_kernel(const float2* __restrict__ um,
                           const float* __restrict__ decw,
                           float* __restrict__ wqd) {
  int l = blockIdx.y;
  int idx = blockIdx.x * 256 + threadIdx.x;
  int i = idx >> 7, c = idx & 127;
  const float2* u = um + (size_t)l * 16384;
  const float* dw = decw + (size_t)l * 16384;
  float acc = 0.f;
  for (int k = 0; k < 128; ++k) acc += u[i * 128 + k].x * dw[k * 128 + c];
  wqd[(size_t)l * 16384 + idx] = acc;
}

// ==================== UV precompute: U=h@W1top, V=h@W1bot ==================
// GEMM1 of the edge MLP is separable: m_pre = U[row]+V[col]+radial*w256+
// ea*w257+b1. Computing U,V per NODE (2 GF) removes 9/13 of per-edge MFMA,
// the 288-col A-tile, and its bank conflicts from the edge kernels.
__global__ __launch_bounds__(256, 2) void uv_kernel(
    const float* __restrict__ h, const ushort* __restrict__ w1cs,
    ushort* __restrict__ UV) {
  __shared__ ushort A[EPB * MS];
  const int tid = threadIdx.x;
  const int n0 = blockIdx.x * EPB;
  const int lane = tid & 63, wave = tid >> 6;
  const int lrow = lane & 15, lq = lane >> 4;
  const int wbase = wave * 32;
  const int woff0 = (wbase + lrow) * 32 + lq * 8;
  const int woff1 = (wbase + 16 + lrow) * 32 + lq * 8;

  {
    const int e = tid >> 2, j = tid & 3;
    int node = n0 + e;
    if (node >= N_NODES) node = N_NODES - 1;
    const float4* s4 = (const float4*)(h + (size_t)node * HDIM + j * 32);
    ushort* dst = A + e * MS + j * 32;
#pragma unroll
    for (int i = 0; i < 8; ++i) {
      float4 v = s4[i];
      ushort4 o;
      o.x = f2bf(v.x); o.y = f2bf(v.y); o.z = f2bf(v.z); o.w = f2bf(v.w);
      ((ushort4*)dst)[i] = o;
    }
  }
  __syncthreads();

  f32x4 aU[4][2], aV[4][2];
#pragma unroll
  for (int mt = 0; mt < 4; ++mt)
#pragma unroll
    for (int nt = 0; nt < 2; ++nt) {
      aU[mt][nt] = (f32x4){0.f, 0.f, 0.f, 0.f};
      aV[mt][nt] = (f32x4){0.f, 0.f, 0.f, 0.f};
    }
#pragma unroll
  for (int kt = 0; kt < 4; ++kt) {
    short8b af[4];
#pragma unroll
    for (int mt = 0; mt < 4; ++mt)
      af[mt] = *(const short8b*)(A + (mt * 16 + lrow) * MS + kt * 32 + lq * 8);
    short8b u0 = *(const short8b*)(w1cs + kt * 4096 + woff0);
    short8b u1 = *(const short8b*)(w1cs + kt * 4096 + woff1);
    short8b v0 = *(const short8b*)(w1cs + (kt + 4) * 4096 + woff0);
    short8b v1 = *(const short8b*)(w1cs + (kt + 4) * 4096 + woff1);
#pragma unroll
    for (int mt = 0; mt < 4; ++mt) {
      aU[mt][0] = __builtin_amdgcn_mfma_f32_16x16x32_bf16(af[mt], u0, aU[mt][0], 0, 0, 0);
      aU[mt][1] = __builtin_amdgcn_mfma_f32_16x16x32_bf16(af[mt], u1, aU[mt][1], 0, 0, 0);
      aV[mt][0] = __builtin_amdgcn_mfma_f32_16x16x32_bf16(af[mt], v0, aV[mt][0], 0, 0, 0);
      aV[mt][1] = __builtin_amdgcn_mfma_f32_16x16x32_bf16(af[mt], v1, aV[mt][1], 0, 0, 0);
    }
  }
#pragma unroll
  for (int mt = 0; mt < 4; ++mt)
#pragma unroll
    for (int nt = 0; nt < 2; ++nt) {
      const int col = wbase + nt * 16 + lrow;
#pragma unroll
      for (int r = 0; r < 4; ++r) {
        const int node = n0 + mt * 16 + lq * 4 + r;
        if (node < N_NODES) {
          UV[(size_t)node * 256 + col] = f2bf(aU[mt][nt][r]);
          UV[(size_t)node * 256 + 128 + col] = f2bf(aV[mt][nt][r]);
        }
      }
    }
}

// ==================== edge MLP: UV gather + silu + GEMM2, atomic-free ======
__global__ __launch_bounds__(256, 8) void edge_mfma_kernel(
    const ushort* __restrict__ UV, const int* __restrict__ ei,
    const float* __restrict__ x, const float* __restrict__ ea,
    const int* __restrict__ elist, const int* __restrict__ cstart,
    const ushort* __restrict__ w1cs, const float* __restrict__ b1,
    const ushort* __restrict__ w2cs, const float* __restrict__ b2,
    ushort* __restrict__ aggb, ushort* __restrict__ headpb) {
  __shared__ ushort m1[EPB * MS];   // m1 then m2 (both bf16) overlay
  __shared__ float wrow[384];       // W1 radial row, ea row, b1
  __shared__ int rows[EPB];

  const int tid = threadIdx.x;
  const int lane = tid & 63, wave = tid >> 6;
  const int lrow = lane & 15, lq = lane >> 4;
  const int wbase = wave * 32;
  const int woff0 = (wbase + lrow) * 32 + lq * 8;
  const int woff1 = (wbase + 16 + lrow) * 32 + lq * 8;
  const float b2v[2] = {b2[wbase + lrow], b2[wbase + 16 + lrow]};

  if (tid < 128) {
    wrow[tid] = bf2f(w1cs[8 * 4096 + tid * 32 + 0]);
    wrow[128 + tid] = bf2f(w1cs[8 * 4096 + tid * 32 + 1]);
    wrow[256 + tid] = b1[tid];
  }

  const int i0 = blockIdx.x * EPB;
  const int e = tid >> 2, j = tid & 3;
  const int edge = elist[i0 + e];
  const int r = ei[edge], c = ei[N_EDGES + edge];
  if (j == 0) rows[e] = r;
  float dx = x[r * 3 + 0] - x[c * 3 + 0];
  float dy = x[r * 3 + 1] - x[c * 3 + 1];
  float dz = x[r * 3 + 2] - x[c * 3 + 2];
  const float radial = dx * dx + dy * dy + dz * dz;
  const float eav = ea[edge];
  const uint4* up = (const uint4*)(UV + (size_t)r * 256 + j * 32);
  const uint4* vp = (const uint4*)(UV + (size_t)c * 256 + 128 + j * 32);
  uint4 u[4] = {up[0], up[1], up[2], up[3]};
  uint4 v[4] = {vp[0], vp[1], vp[2], vp[3]};
  __syncthreads();   // wrow ready

#pragma unroll
  for (int q4 = 0; q4 < 4; ++q4) {
    const uint* uu = (const uint*)&u[q4];
    const uint* vv = (const uint*)&v[q4];
    uint wv[4];
#pragma unroll
    for (int t = 0; t < 4; ++t) {
      const int col = j * 32 + q4 * 8 + t * 2;
      float a0 = __uint_as_float(uu[t] << 16) + __uint_as_float(vv[t] << 16) + wrow[256 + col];
      float a1 = __uint_as_float(uu[t] & 0xffff0000u) + __uint_as_float(vv[t] & 0xffff0000u) + wrow[256 + col + 1];
      a0 = fmaf(radial, wrow[col], a0);
      a1 = fmaf(radial, wrow[col + 1], a1);
      a0 = fmaf(eav, wrow[128 + col], a0);
      a1 = fmaf(eav, wrow[128 + col + 1], a1);
      wv[t] = (uint)f2bf(silu_f(a0)) | ((uint)f2bf(silu_f(a1)) << 16);
    }
    *(uint4*)(m1 + e * MS + j * 32 + q4 * 8) = make_uint4(wv[0], wv[1], wv[2], wv[3]);
  }
  __syncthreads();   // m1 ready

  f32x4 acc2[4][2];
#pragma unroll
  for (int mt = 0; mt < 4; ++mt)
#pragma unroll
    for (int nt = 0; nt < 2; ++nt) acc2[mt][nt] = (f32x4){0.f, 0.f, 0.f, 0.f};
  {
    short8b wcur0 = *(const short8b*)(w2cs + woff0);
    short8b wcur1 = *(const short8b*)(w2cs + woff1);
#pragma unroll
    for (int kt = 0; kt < 4; ++kt) {
      short8b wn0, wn1;
      if (kt < 3) {
        wn0 = *(const short8b*)(w2cs + (kt + 1) * 4096 + woff0);
        wn1 = *(const short8b*)(w2cs + (kt + 1) * 4096 + woff1);
      }
      short8b af[4];
#pragma unroll
      for (int mt = 0; mt < 4; ++mt)
        af[mt] = *(const short8b*)(m1 + (mt * 16 + lrow) * MS + kt * 32 + lq * 8);
#pragma unroll
      for (int mt = 0; mt < 4; ++mt) {
        acc2[mt][0] = __builtin_amdgcn_mfma_f32_16x16x32_bf16(af[mt], wcur0, acc2[mt][0], 0, 0, 0);
        acc2[mt][1] = __builtin_amdgcn_mfma_f32_16x16x32_bf16(af[mt], wcur1, acc2[mt][1], 0, 0, 0);
      }
      if (kt < 3) { wcur0 = wn0; wcur1 = wn1; }
    }
  }
  __syncthreads();   // all m1 reads done (m2 overlays)
#pragma unroll
  for (int mt = 0; mt < 4; ++mt)
#pragma unroll
    for (int nt = 0; nt < 2; ++nt)
#pragma unroll
      for (int r2 = 0; r2 < 4; ++r2)
        m1[(mt * 16 + lq * 4 + r2) * MS + wbase + nt * 16 + lrow] =
            f2bf(silu_f(acc2[mt][nt][r2] + b2v[nt]));
  __syncthreads();   // m2 ready

  // ---- segmented reduce over sorted rows; bf16 plain stores, no atomics ---
  const int e2 = tid & 63, cg = tid >> 6, cb = cg * 32;
  const int r_e = rows[e2];
  const bool leader = (e2 == 0) || (rows[e2 - 1] != r_e);
  if (leader) {
    float sum[32];
    {
      const uint4* mr = (const uint4*)(m1 + e2 * MS + cb);
#pragma unroll
      for (int q4 = 0; q4 < 4; ++q4) {
        uint4 w = mr[q4];
        const uint* wp = (const uint*)&w;
#pragma unroll
        for (int t = 0; t < 4; ++t) {
          sum[q4 * 8 + t * 2] = __uint_as_float(wp[t] << 16);
          sum[q4 * 8 + t * 2 + 1] = __uint_as_float(wp[t] & 0xffff0000u);
        }
      }
    }
    int f = e2 + 1;
    while (f < EPB && rows[f] == r_e) {
      const uint4* mr = (const uint4*)(m1 + f * MS + cb);
#pragma unroll
      for (int q4 = 0; q4 < 4; ++q4) {
        uint4 w = mr[q4];
        const uint* wp = (const uint*)&w;
#pragma unroll
        for (int t = 0; t < 4; ++t) {
          sum[q4 * 8 + t * 2] += __uint_as_float(wp[t] << 16);
          sum[q4 * 8 + t * 2 + 1] += __uint_as_float(wp[t] & 0xffff0000u);
        }
      }
      ++f;
    }
    ushort* dstp = (e2 == 0 && cstart[r_e] < i0)
                       ? headpb + (size_t)blockIdx.x * HDIM + cb   // continuation
                       : aggb + (size_t)r_e * HDIM + cb;           // sole writer
#pragma unroll
    for (int q4 = 0; q4 < 4; ++q4) {
      uint wv[4];
#pragma unroll
      for (int t = 0; t < 4; ++t)
        wv[t] = (uint)f2bf(sum[q4 * 8 + t * 2]) | ((uint)f2bf(sum[q4 * 8 + t * 2 + 1]) << 16);
      *(uint4*)(dstp + q4 * 8) = make_uint4(wv[0], wv[1], wv[2], wv[3]);
    }
  }
}

// ==================== MFMA node update (folds bf16 headp) ==================
__global__ __launch_bounds__(256, 2) void node_mfma_kernel(
    float* __restrict__ out_h, const ushort* __restrict__ aggb,
    const int* __restrict__ cstart, const int* __restrict__ cend,
    const ushort* __restrict__ headpb,
    const ushort* __restrict__ enccs, const float* __restrict__ encb,
    const ushort* __restrict__ wqdcs, const float* __restrict__ decb) {
  __shared__ ushort A[EPB * NAS];
  __shared__ ushort m1[EPB * MS];
  __shared__ float nbuf[4 * EPB];
  const int tid = threadIdx.x;
  const int n0 = blockIdx.x * EPB;

  const int lane = tid & 63, wave = tid >> 6;
  const int lrow = lane & 15, lq = lane >> 4;
  const int wbase = wave * 32;

  short8b wef[8][2], wqf[4][2];
#pragma unroll
  for (int kt = 0; kt < 8; ++kt)
#pragma unroll
    for (int nt = 0; nt < 2; ++nt)
      wef[kt][nt] = *(const short8b*)(enccs + kt * 4096 + (wbase + nt * 16 + lrow) * 32 + lq * 8);
#pragma unroll
  for (int kt = 0; kt < 4; ++kt)
#pragma unroll
    for (int nt = 0; nt < 2; ++nt)
      wqf[kt][nt] = *(const short8b*)(wqdcs + kt * 4096 + (wbase + nt * 16 + lrow) * 32 + lq * 8);
  const float ebv[2] = {encb[wbase + lrow], encb[wbase + 16 + lrow]};
  const float dbv[2] = {decb[wbase + lrow], decb[wbase + 16 + lrow]};

  {
    const int e = tid >> 2, j = tid & 3;
    int node = n0 + e;
    if (node >= N_NODES) node = N_NODES - 1;
    if (j < 2) {
      const float4* s4 = (const float4*)(out_h + (size_t)node * HDIM + j * 64);
      ushort* dst = A + e * NAS + j * 64;
#pragma unroll
      for (int i = 0; i < 16; ++i) {
        float4 v = s4[i];
        ushort4 o;
        o.x = f2bf(v.x); o.y = f2bf(v.y); o.z = f2bf(v.z); o.w = f2bf(v.w);
        ((ushort4*)dst)[i] = o;
      }
    } else {
      const int s = cstart[node], en = cend[node];
      const bool hasAgg = en > s;
      const uint4* a4 = (const uint4*)(aggb + (size_t)node * HDIM + (j - 2) * 64);
      const int bb0 = (s >> 6) + 1;
      const int bb1 = hasAgg ? ((en - 1) >> 6) : 0;
      ushort* dst = A + e * NAS + 128 + (j - 2) * 64;
#pragma unroll
      for (int i = 0; i < 8; ++i) {
        float f[8];
        if (hasAgg) {
          uint4 w = a4[i];
          const uint* wp = (const uint*)&w;
#pragma unroll
          for (int t = 0; t < 4; ++t) {
            f[t * 2] = __uint_as_float(wp[t] << 16);
            f[t * 2 + 1] = __uint_as_float(wp[t] & 0xffff0000u);
          }
        } else {
#pragma unroll
          for (int t = 0; t < 8; ++t) f[t] = 0.f;
        }
        for (int bb = bb0; bb <= bb1; ++bb) {
          uint4 hw = *(const uint4*)(headpb + (size_t)bb * HDIM + (j - 2) * 64 + i * 8);
          const uint* hp = (const uint*)&hw;
#pragma unroll
          for (int t = 0; t < 4; ++t) {
            f[t * 2] += __uint_as_float(hp[t] << 16);
            f[t * 2 + 1] += __uint_as_float(hp[t] & 0xffff0000u);
          }
        }
        uint wv[4];
#pragma unroll
        for (int t = 0; t < 4; ++t)
          wv[t] = (uint)f2bf(f[t * 2] * 0.01f) | ((uint)f2bf(f[t * 2 + 1] * 0.01f) << 16);
        *(uint4*)(dst + i * 8) = make_uint4(wv[0], wv[1], wv[2], wv[3]);
      }
    }
  }
  __syncthreads();

  f32x4 acc[4][2];
#pragma unroll
  for (int mt = 0; mt < 4; ++mt)
#pragma unroll
    for (int nt = 0; nt < 2; ++nt) acc[mt][nt] = (f32x4){0.f, 0.f, 0.f, 0.f};
#pragma unroll
  for (int kt = 0; kt < 8; ++kt) {
    short8b af[4];
#pragma unroll
    for (int mt = 0; mt < 4; ++mt)
      af[mt] = *(const short8b*)(A + (mt * 16 + lrow) * NAS + kt * 32 + lq * 8);
#pragma unroll
    for (int mt = 0; mt < 4; ++mt)
#pragma unroll
      for (int nt = 0; nt < 2; ++nt)
        acc[mt][nt] = __builtin_amdgcn_mfma_f32_16x16x32_bf16(af[mt], wef[kt][nt], acc[mt][nt], 0, 0, 0);
  }
#pragma unroll
  for (int mt = 0; mt < 4; ++mt) {
    float ssp[4] = {0.f, 0.f, 0.f, 0.f};
#pragma unroll
    for (int nt = 0; nt < 2; ++nt)
#pragma unroll
      for (int r = 0; r < 4; ++r) {
        acc[mt][nt][r] += ebv[nt];
        ssp[r] += acc[mt][nt][r] * acc[mt][nt][r];
      }
#pragma unroll
    for (int m = 1; m < 16; m <<= 1)
#pragma unroll
      for (int r = 0; r < 4; ++r) ssp[r] += __shfl_xor(ssp[r], m, 64);
    if (lrow == 0) {
#pragma unroll
      for (int r = 0; r < 4; ++r)
        nbuf[wave * EPB + mt * 16 + lq * 4 + r] = ssp[r];
    }
  }
  __syncthreads();
#pragma unroll
  for (int mt = 0; mt < 4; ++mt)
#pragma unroll
    for (int r = 0; r < 4; ++r) {
      const int row = mt * 16 + lq * 4 + r;
      float sum = nbuf[row] + nbuf[EPB + row] + nbuf[2 * EPB + row] + nbuf[3 * EPB + row];
      float inv = 1.0f / sqrtf(sum + 1e-12f);
#pragma unroll
      for (int nt = 0; nt < 2; ++nt)
        m1[row * MS + wbase + nt * 16 + lrow] = f2bf(acc[mt][nt][r] * inv);
    }
  __syncthreads();

  f32x4 acc2[4][2];
#pragma unroll
  for (int mt = 0; mt < 4; ++mt)
#pragma unroll
    for (int nt = 0; nt < 2; ++nt) acc2[mt][nt] = (f32x4){0.f, 0.f, 0.f, 0.f};
#pragma unroll
  for (int kt = 0; kt < 4; ++kt) {
    short8b af[4];
#pragma unroll
    for (int mt = 0; mt < 4; ++mt)
      af[mt] = *(const short8b*)(m1 + (mt * 16 + lrow) * MS + kt * 32 + lq * 8);
#pragma unroll
    for (int mt = 0; mt < 4; ++mt)
#pragma unroll
      for (int nt = 0; nt < 2; ++nt)
        acc2[mt][nt] = __builtin_amdgcn_mfma_f32_16x16x32_bf16(af[mt], wqf[kt][nt], acc2[mt][nt], 0, 0, 0);
  }
#pragma unroll
  for (int mt = 0; mt < 4; ++mt)
#pragma unroll
    for (int nt = 0; nt < 2; ++nt) {
      const int n = wbase + nt * 16 + lrow;
#pragma unroll
      for (int r = 0; r < 4; ++r) {
        const int node = n0 + mt * 16 + lq * 4 + r;
        if (node < N_NODES) {
          size_t off = (size_t)node * HDIM + n;
          out_h[off] = out_h[off] + acc2[mt][nt][r] + dbv[nt];
        }
      }
    }
}

// ==================== coord head: UV gather + silu + GEMM2 =================
__global__ __launch_bounds__(256, 7) void coord_mfma_kernel(
    const ushort* __restrict__ UV, const int* __restrict__ ei,
    const float* __restrict__ x, const float* __restrict__ ea,
    const int* __restrict__ elist,
    const ushort* __restrict__ w1cs, const float* __restrict__ b1,
    const ushort* __restrict__ w2cs, const float* __restrict__ b2,
    const float* __restrict__ w3, float* __restrict__ xout) {
  __shared__ ushort m1[EPB * MS];
  __shared__ float wrow[384];
  __shared__ int rows[EPB];
  __shared__ int colsA[EPB];
  __shared__ float pbuf[4 * EPB];
  __shared__ float tv[EPB];

  const int tid = threadIdx.x;
  const int lane = tid & 63, wave = tid >> 6;
  const int lrow = lane & 15, lq = lane >> 4;
  const int wbase = wave * 32;
  const int woff0 = (wbase + lrow) * 32 + lq * 8;
  const int woff1 = (wbase + 16 + lrow) * 32 + lq * 8;
  const float b2v[2] = {b2[wbase + lrow], b2[wbase + 16 + lrow]};
  const float w3v[2] = {w3[wbase + lrow], w3[wbase + 16 + lrow]};

  if (tid < 128) {
    wrow[tid] = bf2f(w1cs[8 * 4096 + tid * 32 + 0]);
    wrow[128 + tid] = bf2f(w1cs[8 * 4096 + tid * 32 + 1]);
    wrow[256 + tid] = b1[tid];
  }

  const int i0 = blockIdx.x * EPB;
  const int e = tid >> 2, j = tid & 3;
  const int edge = elist[i0 + e];
  const int r = ei[edge], c = ei[N_EDGES + edge];
  if (j == 0) { rows[e] = r; colsA[e] = c; }
  float dx = x[r * 3 + 0] - x[c * 3 + 0];
  float dy = x[r * 3 + 1] - x[c * 3 + 1];
  float dz = x[r * 3 + 2] - x[c * 3 + 2];
  const float radial = dx * dx + dy * dy + dz * dz;
  const float eav = ea[edge];
  const uint4* up = (const uint4*)(UV + (size_t)r * 256 + j * 32);
  const uint4* vp = (const uint4*)(UV + (size_t)c * 256 + 128 + j * 32);
  uint4 u[4] = {up[0], up[1], up[2], up[3]};
  uint4 v[4] = {vp[0], vp[1], vp[2], vp[3]};
  __syncthreads();

#pragma unroll
  for (int q4 = 0; q4 < 4; ++q4) {
    const uint* uu = (const uint*)&u[q4];
    const uint* vv = (const uint*)&v[q4];
    uint wv[4];
#pragma unroll
    for (int t = 0; t < 4; ++t) {
      const int col = j * 32 + q4 * 8 + t * 2;
      float a0 = __uint_as_float(uu[t] << 16) + __uint_as_float(vv[t] << 16) + wrow[256 + col];
      float a1 = __uint_as_float(uu[t] & 0xffff0000u) + __uint_as_float(vv[t] & 0xffff0000u) + wrow[256 + col + 1];
      a0 = fmaf(radial, wrow[col], a0);
      a1 = fmaf(radial, wrow[col + 1], a1);
      a0 = fmaf(eav, wrow[128 + col], a0);
      a1 = fmaf(eav, wrow[128 + col + 1], a1);
      wv[t] = (uint)f2bf(silu_f(a0)) | ((uint)f2bf(silu_f(a1)) << 16);
    }
    *(uint4*)(m1 + e * MS + j * 32 + q4 * 8) = make_uint4(wv[0], wv[1], wv[2], wv[3]);
  }
  __syncthreads();

  f32x4 acc2[4][2];
#pragma unroll
  for (int mt = 0; mt < 4; ++mt)
#pragma unroll
    for (int nt = 0; nt < 2; ++nt) acc2[mt][nt] = (f32x4){0.f, 0.f, 0.f, 0.f};
  {
    short8b wcur0 = *(const short8b*)(w2cs + woff0);
    short8b wcur1 = *(const short8b*)(w2cs + woff1);
#pragma unroll
    for (int kt = 0; kt < 4; ++kt) {
      short8b wn0, wn1;
      if (kt < 3) {
        wn0 = *(const short8b*)(w2cs + (kt + 1) * 4096 + woff0);
        wn1 = *(const short8b*)(w2cs + (kt + 1) * 4096 + woff1);
      }
      short8b af[4];
#pragma unroll
      for (int mt = 0; mt < 4; ++mt)
        af[mt] = *(const short8b*)(m1 + (mt * 16 + lrow) * MS + kt * 32 + lq * 8);
#pragma unroll
      for (int mt = 0; mt < 4; ++mt) {
        acc2[mt][0] = __builtin_amdgcn_mfma_f32_16x16x32_bf16(af[mt], wcur0, acc2[mt][0], 0, 0, 0);
        acc2[mt][1] = __builtin_amdgcn_mfma_f32_16x16x32_bf16(af[mt], wcur1, acc2[mt][1], 0, 0, 0);
      }
      if (kt < 3) { wcur0 = wn0; wcur1 = wn1; }
    }
  }
#pragma unroll
  for (int mt = 0; mt < 4; ++mt) {
    float p[4] = {0.f, 0.f, 0.f, 0.f};
#pragma unroll
    for (int nt = 0; nt < 2; ++nt)
#pragma unroll
      for (int r2 = 0; r2 < 4; ++r2)
        p[r2] += silu_f(acc2[mt][nt][r2] + b2v[nt]) * w3v[nt];
#pragma unroll
    for (int m = 1; m < 16; m <<= 1)
#pragma unroll
      for (int r2 = 0; r2 < 4; ++r2) p[r2] += __shfl_xor(p[r2], m, 64);
    if (lrow == 0) {
#pragma unroll
      for (int r2 = 0; r2 < 4; ++r2)
        pbuf[wave * EPB + mt * 16 + lq * 4 + r2] = p[r2];
    }
  }
  __syncthreads();
  if (tid < EPB) {
    tv[tid] = (pbuf[tid] + pbuf[EPB + tid] + pbuf[2 * EPB + tid] + pbuf[3 * EPB + tid]) * 0.01f;
  }
  __syncthreads();
  if (tid < EPB) {
    const int e3 = tid;
    const int r_e = rows[e3];
    const bool leader = (e3 == 0) || (rows[e3 - 1] != r_e);
    if (leader) {
      float sx = 0.f, sy = 0.f, sz = 0.f;
      int f = e3;
      do {
        const int cc = colsA[f];
        float ddx = x[r_e * 3 + 0] - x[cc * 3 + 0];
        float ddy = x[r_e * 3 + 1] - x[cc * 3 + 1];
        float ddz = x[r_e * 3 + 2] - x[cc * 3 + 2];
        float rad = ddx * ddx + ddy * ddy + ddz * ddz;
        float s = 1.0f / (sqrtf(rad + 1e-8f) + 1.0f);
        float t = tv[f];
        sx += ddx * s * t; sy += ddy * s * t; sz += ddz * s * t;
        ++f;
      } while (f < EPB && rows[f] == r_e);
      atomicAdd(&xout[r_e * 3 + 0], sx);
      atomicAdd(&xout[r_e * 3 + 1], sy);
      atomicAdd(&xout[r_e * 3 + 2], sz);
    }
  }
}

extern "C" void kernel_launch(void* const* d_in, const int* in_sizes, int n_in,
                              void* d_out, int out_size, void* d_ws, size_t ws_size,
                              hipStream_t stream) {
  const float* h     = (const float*)d_in[0];
  const float* x     = (const float*)d_in[1];
  const int*   ei    = (const int*)d_in[2];
  const float* ea    = (const float*)d_in[3];
  const float* e_w1  = (const float*)d_in[4];
  const float* e_b1  = (const float*)d_in[5];
  const float* e_w2  = (const float*)d_in[6];
  const float* e_b2  = (const float*)d_in[7];
  const float* enc_w = (const float*)d_in[8];
  const float* enc_b = (const float*)d_in[9];
  const float* coeffs= (const float*)d_in[10];
  const float* A_re  = (const float*)d_in[11];
  const float* A_im  = (const float*)d_in[12];
  const float* dec_w = (const float*)d_in[13];
  const float* dec_b = (const float*)d_in[14];
  const float* c_w1  = (const float*)d_in[15];
  const float* c_b1  = (const float*)d_in[16];
  const float* c_w2  = (const float*)d_in[17];
  const float* c_b2  = (const float*)d_in[18];
  const float* c_w3  = (const float*)d_in[19];

  float* out = (float*)d_out;
  float* ws  = (float*)d_ws;

  // workspace layout (float offsets) — total 6,909,152 f = 27.6 MB
  ushort* aggb   = (ushort*)ws;                     // 30000*128 bf16
  int*    cursor = (int*)(ws + 1920000);            // 30,000
  int*    cstart = (int*)(ws + 1950000);            // 30,000
  int*    elist  = (int*)(ws + 1980000);            // 480,000
  ushort* headpb = (ushort*)(ws + 2460000);         // 7500*128 bf16
  ushort* w1cs   = (ushort*)(ws + 2940000);         // 2*9*4096 us
  ushort* w2cs   = (ushort*)(ws + 2976864);         // 2*4*4096 us
  ushort* cw1cs  = (ushort*)(ws + 2993248);         // 9*4096 us
  ushort* cw2cs  = (ushort*)(ws + 3011680);         // 4*4096 us
  ushort* enccs  = (ushort*)(ws + 3019872);         // 2*8*4096 us
  ushort* wqdcs  = (ushort*)(ws + 3052640);         // 2*4*4096 us
  int*    perm   = (int*)(ws + 3069024);            // 128
  ushort* UVb    = (ushort*)(ws + 3069152);         // 30000*256 bf16
  // quantum temps overlay the UV region (dead before first uv_kernel write)
  float2* xa  = (float2*)(ws + 3069152);
  float2* xb  = (float2*)(ws + 3069152 + 131072);
  float2* xt  = (float2*)(ws + 3069152 + 262144);
  float2* qm  = (float2*)(ws + 3069152 + 393216);
  float2* gkm = (float2*)(ws + 3069152 + 524288);
  float2* njm = (float2*)(ws + 3069152 + 655360);
  float2* um  = (float2*)(ws + 3069152 + 786432);
  float*  wqd = ws + 3069152 + 851968;

  init_out_kernel<<<15000, 256, 0, stream>>>(h, x, out);

  // counting sort of edges by destination row
  hipMemsetAsync(cursor, 0, N_NODES * sizeof(int), stream);
  count_kernel<<<1875, 256, 0, stream>>>(ei, cursor);
  scan_kernel<<<1, 1024, 0, stream>>>(cursor, cstart);
  fill_kernel<<<1875, 256, 0, stream>>>(ei, cursor, elist);

  // quantum-operator precompute: Newton-Schulz inverse + tiny GEMM chain
  perm_kernel<<<1, 128, 0, stream>>>(perm);
  ns_init_kernel<<<dim3(64, 4), 256, 0, stream>>>(A_re, A_im, xa);
  float2* cur = xa;
  float2* nxt = xb;
  for (int it = 0; it < 4; ++it) {
    ns_bx_kernel<<<dim3(64, 4), 256, 0, stream>>>(A_re, A_im, cur, xt);
    ns_upd_kernel<<<dim3(64, 4), 256, 0, stream>>>(cur, xt, nxt);
    float2* tmp = cur; cur = nxt; nxt = tmp;
  }
  qmat_kernel<<<dim3(64, 4), 256, 0, stream>>>(A_re, A_im, cur, qm);
  gk_kernel<<<dim3(64, 4), 256, 0, stream>>>(coeffs, gkm);
  nj_kernel<<<dim3(64, 4), 256, 0, stream>>>(qm, gkm, perm, njm);
  compose_kernel<<<dim3(64, 2), 256, 0, stream>>>(njm, um);
  wqd_kernel<<<dim3(64, 2), 256, 0, stream>>>(um, dec_w, wqd);

  // weight conversions to chunked bf16 [kt][n][kk] (wqdcs BEFORE UV overlay)
  for (int l = 0; l < 2; ++l) {
    convert_w_kernel<<<144, 256, 0, stream>>>(e_w1 + (size_t)l * 258 * HDIM,
                                              w1cs + (size_t)l * 9 * 4096, 258, 9);
    convert_w_kernel<<<64, 256, 0, stream>>>(e_w2 + (size_t)l * HDIM * HDIM,
                                             w2cs + (size_t)l * 4 * 4096, 128, 4);
    convert_w_kernel<<<128, 256, 0, stream>>>(enc_w + (size_t)l * 256 * HDIM,
                                              enccs + (size_t)l * 8 * 4096, 256, 8);
    convert_w_kernel<<<64, 256, 0, stream>>>(wqd + (size_t)l * HDIM * HDIM,
                                             wqdcs + (size_t)l * 4 * 4096, 128, 4);
  }
  convert_w_kernel<<<144, 256, 0, stream>>>(c_w1, cw1cs, 258, 9);
  convert_w_kernel<<<64, 256, 0, stream>>>(c_w2, cw2cs, 128, 4);

  // two message-passing layers
  const int NB = (N_NODES + EPB - 1) / EPB;
  for (int l = 0; l < 2; ++l) {
    uv_kernel<<<NB, 256, 0, stream>>>(out, w1cs + (size_t)l * 9 * 4096, UVb);
    edge_mfma_kernel<<<N_EDGES / EPB, 256, 0, stream>>>(
        UVb, ei, x, ea, elist, cstart,
        w1cs + (size_t)l * 9 * 4096, e_b1 + l * HDIM,
        w2cs + (size_t)l * 4 * 4096, e_b2 + l * HDIM, aggb, headpb);
    node_mfma_kernel<<<NB, 256, 0, stream>>>(
        out, aggb, cstart, cursor, headpb,
        enccs + (size_t)l * 8 * 4096, enc_b + l * HDIM,
        wqdcs + (size_t)l * 4 * 4096, dec_b + l * HDIM);
  }

  // coordinate head
  uv_kernel<<<NB, 256, 0, stream>>>(out, cw1cs, UVb);
  coord_mfma_kernel<<<N_EDGES / EPB, 256, 0, stream>>>(
      UVb, ei, x, ea, elist, cw1cs, c_b1, cw2cs, c_b2, c_w3,
      out + (size_t)N_NODES * HDIM);
}